// Round 1
// baseline (546.666 us; speedup 1.0000x reference)
//
#include <hip/hip_runtime.h>

// Problem constants (from reference): VOCAB=8, EMB=128, B=4, L=512.
// out[b,i,j,d] = (table[x[b,i]] @ W1)[d] + (table[x[b,j]] @ W2)[d] + bias[d]
// Only 8 distinct P1 rows and 8 distinct P2 rows exist -> precompute the
// 64 combined rows C[vi][vj][0:128] once, then the output is a pure
// table-lookup write stream (536.9 MB fp32) -> HBM-write-bound.

#define VOCAB 8
#define EMB   128
#define BATCH 4
#define LEN   512

// ---------------------------------------------------------------------------
// Kernel A: one block. Compute P1 = table@W[:128], P2 = table@W[128:] + bias,
// then C[vi*8+vj][d] = P1[vi][d] + P2[vj][d]. C is 64*128 fp32 = 32 KB in d_ws.
// ---------------------------------------------------------------------------
__global__ __launch_bounds__(256) void build_C(const float* __restrict__ table,
                                               const float* __restrict__ W,
                                               const float* __restrict__ bias,
                                               float* __restrict__ C) {
    __shared__ float P1[VOCAB][EMB];
    __shared__ float P2[VOCAB][EMB];
    const int t = threadIdx.x;

    // 8*128 = 1024 outputs per P matrix; 256 threads -> 4 each.
    for (int idx = t; idx < VOCAB * EMB; idx += 256) {
        const int v = idx >> 7;      // vocab id
        const int d = idx & 127;     // output dim
        float s1 = 0.f, s2 = 0.f;
        #pragma unroll 8
        for (int k = 0; k < EMB; ++k) {
            const float e = table[v * EMB + k];
            s1 += e * W[k * EMB + d];            // W1 rows 0..127
            s2 += e * W[(EMB + k) * EMB + d];    // W2 rows 128..255
        }
        P1[v][d] = s1;
        P2[v][d] = s2 + bias[d];                 // fold bias into P2
    }
    __syncthreads();

    // 64*128 = 8192 combined entries.
    for (int idx = t; idx < VOCAB * VOCAB * EMB; idx += 256) {
        const int d  = idx & 127;
        const int vj = (idx >> 7) & 7;
        const int vi = idx >> 10;
        C[idx] = P1[vi][d] + P2[vj][d];
    }
}

// ---------------------------------------------------------------------------
// Kernel B: one block per (b,i). Stage C[vi][0..7] (4 KB) and x[b,:] (2 KB)
// in LDS, then stream float4 stores. Thread t: d-group = t&31 (16B chunk),
// j-sublane = t>>5 (8 j's per iteration). Wave of 64 lanes writes 1024
// contiguous bytes -> perfectly coalesced.
// ---------------------------------------------------------------------------
__global__ __launch_bounds__(256) void write_out(const int* __restrict__ x,
                                                 const float* __restrict__ C,
                                                 float* __restrict__ out) {
    const int bi = blockIdx.x;        // 0..2047
    const int b  = bi >> 9;           // batch
    const int i  = bi & 511;          // query position
    const int t  = threadIdx.x;
    const int dg = t & 31;            // which float4 of the 128-float row
    const int js = t >> 5;            // j sub-index 0..7

    __shared__ float4 Crow[VOCAB][EMB / 4];   // 8 rows x 32 float4 = 4 KB
    __shared__ int    xrow[LEN];              // 2 KB

    const int* xb = x + b * LEN;
    for (int j = t; j < LEN; j += 256) xrow[j] = xb[j];

    const int vi = xb[i];             // uniform across block (scalar load)

    // Stage the 8 candidate rows C[vi*8 + 0..7]: 256 float4, one per thread.
    const float4* Cv = (const float4*)(C + (size_t)vi * VOCAB * EMB);
    Crow[t >> 5][t & 31] = Cv[t];
    __syncthreads();

    float4* orow = (float4*)(out + (size_t)bi * LEN * EMB);

    #pragma unroll 4
    for (int j0 = 0; j0 < LEN; j0 += 8) {
        const int j  = j0 + js;
        const int vj = xrow[j];                      // broadcast per 32-group
        orow[(size_t)j * (EMB / 4) + dg] = Crow[vj][dg];
    }
}

extern "C" void kernel_launch(void* const* d_in, const int* in_sizes, int n_in,
                              void* d_out, int out_size, void* d_ws, size_t ws_size,
                              hipStream_t stream) {
    const int*   x     = (const int*)d_in[0];     // (4,512) int32
    const float* table = (const float*)d_in[1];   // (8,128) f32
    const float* W     = (const float*)d_in[2];   // (256,128) f32
    const float* bias  = (const float*)d_in[3];   // (128,) f32
    float*       out   = (float*)d_out;           // (4,512,512,128) f32
    float*       C     = (float*)d_ws;            // 32 KB scratch

    build_C<<<1, 256, 0, stream>>>(table, W, bias, C);
    write_out<<<BATCH * LEN, 256, 0, stream>>>(x, C, out);
}

// Round 3
// 529.359 us; speedup vs baseline: 1.0327x; 1.0327x over previous
//
#include <hip/hip_runtime.h>

// out[b,i,j,d] = (table[x[b,i]] @ W1)[d] + (table[x[b,j]] @ W2)[d] + bias[d]
// VOCAB=8 -> only 64 distinct 128-float output rows. Precompute all 64
// combined rows C[vi][vj][:] (32 KB) in parallel (64 blocks), then the main
// kernel is a pure gather->write stream: 536.9 MB fp32 stores, HBM-write-bound.

#define VOCAB 8
#define EMB   128
#define BATCH 4
#define LEN   512

typedef float v4f __attribute__((ext_vector_type(4)));

// ---------------------------------------------------------------------------
// Kernel A: 64 blocks, one per (vi,vj); 128 threads, one per output dim d.
// C[vi*8+vj][d] = sum_k table[vi,k]*W[k,d] + sum_k table[vj,k]*W[128+k,d] + b[d]
// W reads are coalesced across threads (consecutive d); table rows staged in
// LDS and broadcast. ~2 us across 64 CUs instead of a serialized single block.
// ---------------------------------------------------------------------------
__global__ __launch_bounds__(128) void build_C(const float* __restrict__ table,
                                               const float* __restrict__ W,
                                               const float* __restrict__ bias,
                                               float* __restrict__ C) {
    const int vi = blockIdx.x >> 3;
    const int vj = blockIdx.x & 7;
    const int d  = threadIdx.x;

    __shared__ float t1[EMB];
    __shared__ float t2[EMB];
    t1[d] = table[vi * EMB + d];
    t2[d] = table[vj * EMB + d];
    __syncthreads();

    float s = bias[d];
    #pragma unroll 8
    for (int k = 0; k < EMB; ++k) {
        s += t1[k] * W[k * EMB + d];          // W1 = W[:128]
        s += t2[k] * W[(EMB + k) * EMB + d];  // W2 = W[128:]
    }
    C[(size_t)blockIdx.x * EMB + d] = s;
}

// ---------------------------------------------------------------------------
// Kernel B: one block per (b,i). Stage the 8 candidate rows C[vi][0..7]
// (4 KB) and x[b,:] (2 KB) in LDS, then stream nontemporal float4 stores.
// Thread t: dg = t&31 (which 16B chunk of the row), js = t>>5 (8 j's per
// iter). A wave writes 1024 contiguous bytes -> perfectly coalesced.
// Nontemporal: the 0.5 GiB stream can't live in L2 anyway; skip the
// dirty-line/writeback round trip.
// ---------------------------------------------------------------------------
__global__ __launch_bounds__(256) void write_out(const int* __restrict__ x,
                                                 const float* __restrict__ C,
                                                 float* __restrict__ out) {
    const int bi = blockIdx.x;        // 0..2047
    const int b  = bi >> 9;
    const int i  = bi & 511;
    const int t  = threadIdx.x;
    const int dg = t & 31;
    const int js = t >> 5;

    __shared__ v4f Crow[VOCAB][EMB / 4];   // 8 rows x 32 float4 = 4 KB
    __shared__ int xrow[LEN];              // 2 KB

    const int* xb = x + b * LEN;
    for (int j = t; j < LEN; j += 256) xrow[j] = xb[j];

    const int vi = xb[i];             // uniform across block

    const v4f* Cv = (const v4f*)(C + (size_t)vi * VOCAB * EMB);
    Crow[t >> 5][t & 31] = Cv[t];     // 256 float4 = the 8 rows
    __syncthreads();

    v4f* orow = (v4f*)out + (size_t)bi * LEN * (EMB / 4);

    #pragma unroll 8
    for (int j0 = 0; j0 < LEN; j0 += 8) {
        const int j  = j0 + js;
        const int vj = xrow[j];                       // broadcast per 32-group
        __builtin_nontemporal_store(Crow[vj][dg],
                                    &orow[(size_t)j * (EMB / 4) + dg]);
    }
}

extern "C" void kernel_launch(void* const* d_in, const int* in_sizes, int n_in,
                              void* d_out, int out_size, void* d_ws, size_t ws_size,
                              hipStream_t stream) {
    const int*   x     = (const int*)d_in[0];     // (4,512) int32
    const float* table = (const float*)d_in[1];   // (8,128) f32
    const float* W     = (const float*)d_in[2];   // (256,128) f32
    const float* bias  = (const float*)d_in[3];   // (128,) f32
    float*       out   = (float*)d_out;           // (4,512,512,128) f32
    float*       C     = (float*)d_ws;            // 32 KB scratch

    build_C<<<VOCAB * VOCAB, 128, 0, stream>>>(table, W, bias, C);
    write_out<<<BATCH * LEN, 256, 0, stream>>>(x, C, out);
}